// Round 1
// baseline (1765.918 us; speedup 1.0000x reference)
//
#include <hip/hip_runtime.h>
#include <hip/hip_bf16.h>

#define HID 64
#define IN_EMB 128
#define IN_DIM 130   // 128 emb + deg + seed

// ---------------- Linear1: x1 = concat(emb, deg, seed) @ W1 + b1 ----------------
// One 64-lane group computes one node's 64 output features; W1 staged in LDS.
__global__ __launch_bounds__(256) void lin1_kernel(
    const float* __restrict__ emb, const float* __restrict__ deg,
    const float* __restrict__ seed, const float* __restrict__ W1,
    const float* __restrict__ b1, float* __restrict__ out, int n) {
  __shared__ float sW[IN_DIM * HID];   // 33.3 KB
  for (int i = threadIdx.x; i < IN_DIM * HID; i += blockDim.x) sW[i] = W1[i];
  __syncthreads();

  const int lane  = threadIdx.x & 63;
  const int group = threadIdx.x >> 6;          // 0..3
  const int nodes_per_block = 32;
  const int base = blockIdx.x * nodes_per_block;

  for (int nn = group; nn < nodes_per_block; nn += 4) {
    const int node = base + nn;
    if (node >= n) continue;
    float acc = b1[lane];
    const float* e = emb + (size_t)node * IN_EMB;
#pragma unroll 8
    for (int k = 0; k < IN_EMB; ++k) acc += e[k] * sW[k * HID + lane];
    acc += deg[node]  * sW[IN_EMB * HID + lane];
    acc += seed[node] * sW[(IN_EMB + 1) * HID + lane];
    out[(size_t)node * HID + lane] = acc;
  }
}

// ---------------- SpMM: y[row[e], f] += vals[e] * x[col[e], f] ----------------
// 64 lanes per edge: coalesced 256B gather + 256B atomic scatter.
__global__ __launch_bounds__(256) void spmm_kernel(
    const int* __restrict__ row, const int* __restrict__ col,
    const float* __restrict__ vals, const float* __restrict__ x,
    float* __restrict__ y, int nE) {
  const int lane = threadIdx.x & 63;
  const int e = blockIdx.x * (blockDim.x >> 6) + (threadIdx.x >> 6);
  if (e >= nE) return;
  const int r = row[e];
  const int c = col[e];
  const float v = vals[e];
  const float m = v * x[(size_t)c * HID + lane];
  atomicAdd(&y[(size_t)r * HID + lane], m);
}

// ---------------- Linear2: x2 = relu(y1) @ W2 + b2 (ReLU fused on load) -------
__global__ __launch_bounds__(256) void lin2_kernel(
    const float* __restrict__ yin, const float* __restrict__ W2,
    const float* __restrict__ b2, float* __restrict__ xout, int n) {
  __shared__ float sW[HID * HID];   // 16 KB
  for (int i = threadIdx.x; i < HID * HID; i += blockDim.x) sW[i] = W2[i];
  __syncthreads();

  const int lane  = threadIdx.x & 63;
  const int group = threadIdx.x >> 6;
  const int nodes_per_block = 32;
  const int base = blockIdx.x * nodes_per_block;

  for (int nn = group; nn < nodes_per_block; nn += 4) {
    const int node = base + nn;
    if (node >= n) continue;
    float acc = b2[lane];
    const float* yrow = yin + (size_t)node * HID;
#pragma unroll 8
    for (int k = 0; k < HID; ++k) {
      float v = yrow[k];
      v = v > 0.f ? v : 0.f;
      acc += v * sW[k * HID + lane];
    }
    xout[(size_t)node * HID + lane] = acc;
  }
}

// ---------------- Final: out = sum_i relu(y2[i,:]) . W_out + b_out ------------
__global__ __launch_bounds__(256) void final_kernel(
    const float* __restrict__ y, const float* __restrict__ Wout,
    const float* __restrict__ bout, float* __restrict__ out, int n) {
  const int lane  = threadIdx.x & 63;
  const int group = threadIdx.x >> 6;
  const float wf = Wout[lane];
  float acc = 0.f;
  const int start  = blockIdx.x * (blockDim.x >> 6) + group;
  const int stride = gridDim.x * (blockDim.x >> 6);
  for (int i = start; i < n; i += stride) {
    float v = y[(size_t)i * HID + lane];
    v = v > 0.f ? v : 0.f;
    acc += v * wf;
  }
  // wave reduction over 64 lanes
  for (int off = 32; off; off >>= 1) acc += __shfl_down(acc, off, 64);
  __shared__ float part[4];
  if (lane == 0) part[group] = acc;
  __syncthreads();
  if (threadIdx.x == 0) {
    atomicAdd(out, part[0] + part[1] + part[2] + part[3]);
    if (blockIdx.x == 0) atomicAdd(out, bout[0]);
  }
}

extern "C" void kernel_launch(void* const* d_in, const int* in_sizes, int n_in,
                              void* d_out, int out_size, void* d_ws, size_t ws_size,
                              hipStream_t stream) {
  const float* emb  = (const float*)d_in[0];
  const float* deg  = (const float*)d_in[1];
  const float* seed = (const float*)d_in[2];
  const int*   row  = (const int*)d_in[3];
  const int*   col  = (const int*)d_in[4];
  const float* vals = (const float*)d_in[5];
  const float* W1   = (const float*)d_in[6];
  const float* b1   = (const float*)d_in[7];
  const float* W2   = (const float*)d_in[8];
  const float* b2   = (const float*)d_in[9];
  const float* Wout = (const float*)d_in[10];
  const float* bout = (const float*)d_in[11];
  float* out = (float*)d_out;

  const int n  = in_sizes[0] / IN_EMB;   // 100000
  const int nE = in_sizes[3];            // 3200000

  const size_t buf_elems = (size_t)n * HID;
  float* xa = (float*)d_ws;              // activation buffer A
  float* yb = xa + buf_elems;            // accumulator / activation buffer B

  const int node_blocks = (n + 31) / 32;
  const int edge_blocks = (nE + 3) / 4;

  // Layer 1 dense
  lin1_kernel<<<node_blocks, 256, 0, stream>>>(emb, deg, seed, W1, b1, xa, n);
  // SpMM 1 (zero accumulator first: ws is poisoned each call)
  hipMemsetAsync(yb, 0, buf_elems * sizeof(float), stream);
  spmm_kernel<<<edge_blocks, 256, 0, stream>>>(row, col, vals, xa, yb, nE);
  // Layer 2 dense (ReLU fused on load), overwrite xa
  lin2_kernel<<<node_blocks, 256, 0, stream>>>(yb, W2, b2, xa, n);
  // SpMM 2 into yb (re-zero)
  hipMemsetAsync(yb, 0, buf_elems * sizeof(float), stream);
  spmm_kernel<<<edge_blocks, 256, 0, stream>>>(row, col, vals, xa, yb, nE);
  // Global sum + output dot
  hipMemsetAsync(out, 0, sizeof(float), stream);
  final_kernel<<<1024, 256, 0, stream>>>(yb, Wout, bout, out, n);
}

// Round 2
// 1196.324 us; speedup vs baseline: 1.4761x; 1.4761x over previous
//
#include <hip/hip_runtime.h>
#include <hip/hip_bf16.h>

#define HID 64
#define IN_EMB 128
#define IN_DIM 130   // 128 emb + deg + seed
#define N_NODES_MAX_SCANBLK 1024

// ---------------- CSR build: histogram ----------------
__global__ __launch_bounds__(256) void hist_kernel(const int* __restrict__ row,
                                                   int* __restrict__ cnt, int nE) {
  int e = blockIdx.x * 256 + threadIdx.x;
  if (e < nE) atomicAdd(&cnt[row[e]], 1);
}

// ---------------- CSR build: single-block exclusive scan over N counters -----
__global__ __launch_bounds__(1024) void scan_kernel(const int* __restrict__ cnt,
                                                    int* __restrict__ row_ptr,
                                                    int* __restrict__ pos, int n) {
  __shared__ int sums[N_NODES_MAX_SCANBLK];
  const int tid = threadIdx.x;
  const int per = (n + 1023) / 1024;
  const int start = tid * per;
  const int end = min(start + per, n);
  int s = 0;
  if (start < n) for (int i = start; i < end; ++i) s += cnt[i];
  sums[tid] = s;
  __syncthreads();
  // Hillis-Steele inclusive scan in LDS
  for (int off = 1; off < 1024; off <<= 1) {
    int v = (tid >= off) ? sums[tid - off] : 0;
    __syncthreads();
    sums[tid] += v;
    __syncthreads();
  }
  int run = sums[tid] - s;   // exclusive prefix
  if (start < n) {
    for (int i = start; i < end; ++i) {
      row_ptr[i] = run;
      pos[i] = run;
      run += cnt[i];
    }
    if (end == n) row_ptr[n] = run;   // == nE
  }
}

// ---------------- CSR build: scatter (col,val) into row-sorted order ---------
__global__ __launch_bounds__(256) void scatter_kernel(const int* __restrict__ row,
                                                      const int* __restrict__ col,
                                                      const float* __restrict__ vals,
                                                      int* __restrict__ pos,
                                                      int2* __restrict__ ce, int nE) {
  int e = blockIdx.x * 256 + threadIdx.x;
  if (e >= nE) return;
  int r = row[e];
  int p = atomicAdd(&pos[r], 1);
  ce[p] = make_int2(col[e], __float_as_int(vals[e]));
}

// ---------------- Linear1 ----------------
__global__ __launch_bounds__(256) void lin1_kernel(
    const float* __restrict__ emb, const float* __restrict__ deg,
    const float* __restrict__ seed, const float* __restrict__ W1,
    const float* __restrict__ b1, float* __restrict__ out, int n) {
  __shared__ float sW[IN_DIM * HID];
  for (int i = threadIdx.x; i < IN_DIM * HID; i += blockDim.x) sW[i] = W1[i];
  __syncthreads();

  const int lane  = threadIdx.x & 63;
  const int group = threadIdx.x >> 6;
  const int base = blockIdx.x * 32;

  for (int nn = group; nn < 32; nn += 4) {
    const int node = base + nn;
    if (node >= n) continue;
    float acc = b1[lane];
    const float* e = emb + (size_t)node * IN_EMB;
#pragma unroll 8
    for (int k = 0; k < IN_EMB; ++k) acc += e[k] * sW[k * HID + lane];
    acc += deg[node]  * sW[IN_EMB * HID + lane];
    acc += seed[node] * sW[(IN_EMB + 1) * HID + lane];
    out[(size_t)node * HID + lane] = acc;
  }
}

// ---------------- SpMM (CSR, gather-only) + fused ReLU -----------------------
// One 64-lane group per row; edges unrolled x8 for memory-level parallelism.
__global__ __launch_bounds__(256) void spmm_csr_kernel(
    const int* __restrict__ row_ptr, const int2* __restrict__ ce,
    const float* __restrict__ x, float* __restrict__ y, int n) {
  const int lane = threadIdx.x & 63;
  const int r = blockIdx.x * 4 + (threadIdx.x >> 6);
  if (r >= n) return;
  int i = row_ptr[r];
  const int end = row_ptr[r + 1];
  float acc = 0.f;
  for (; i + 8 <= end; i += 8) {
    int2 e0 = ce[i], e1 = ce[i+1], e2 = ce[i+2], e3 = ce[i+3];
    int2 e4 = ce[i+4], e5 = ce[i+5], e6 = ce[i+6], e7 = ce[i+7];
    float g0 = x[(size_t)e0.x * HID + lane];
    float g1 = x[(size_t)e1.x * HID + lane];
    float g2 = x[(size_t)e2.x * HID + lane];
    float g3 = x[(size_t)e3.x * HID + lane];
    float g4 = x[(size_t)e4.x * HID + lane];
    float g5 = x[(size_t)e5.x * HID + lane];
    float g6 = x[(size_t)e6.x * HID + lane];
    float g7 = x[(size_t)e7.x * HID + lane];
    acc += __int_as_float(e0.y) * g0 + __int_as_float(e1.y) * g1
         + __int_as_float(e2.y) * g2 + __int_as_float(e3.y) * g3
         + __int_as_float(e4.y) * g4 + __int_as_float(e5.y) * g5
         + __int_as_float(e6.y) * g6 + __int_as_float(e7.y) * g7;
  }
  for (; i < end; ++i) {
    int2 e0 = ce[i];
    acc += __int_as_float(e0.y) * x[(size_t)e0.x * HID + lane];
  }
  y[(size_t)r * HID + lane] = fmaxf(acc, 0.f);   // fused ReLU
}

// ---------------- Linear2 (input already ReLU'd) -----------------------------
__global__ __launch_bounds__(256) void lin2_kernel(
    const float* __restrict__ yin, const float* __restrict__ W2,
    const float* __restrict__ b2, float* __restrict__ xout, int n) {
  __shared__ float sW[HID * HID];
  for (int i = threadIdx.x; i < HID * HID; i += blockDim.x) sW[i] = W2[i];
  __syncthreads();

  const int lane  = threadIdx.x & 63;
  const int group = threadIdx.x >> 6;
  const int base = blockIdx.x * 32;

  for (int nn = group; nn < 32; nn += 4) {
    const int node = base + nn;
    if (node >= n) continue;
    float acc = b2[lane];
    const float* yrow = yin + (size_t)node * HID;
#pragma unroll 8
    for (int k = 0; k < HID; ++k) acc += yrow[k] * sW[k * HID + lane];
    xout[(size_t)node * HID + lane] = acc;
  }
}

// ---------------- Final reduce (input already ReLU'd) ------------------------
__global__ __launch_bounds__(256) void final_kernel(
    const float* __restrict__ y, const float* __restrict__ Wout,
    const float* __restrict__ bout, float* __restrict__ out, int n) {
  const int lane  = threadIdx.x & 63;
  const int group = threadIdx.x >> 6;
  const float wf = Wout[lane];
  float acc = 0.f;
  const int start  = blockIdx.x * (blockDim.x >> 6) + group;
  const int stride = gridDim.x * (blockDim.x >> 6);
  for (int i = start; i < n; i += stride)
    acc += y[(size_t)i * HID + lane] * wf;
  for (int off = 32; off; off >>= 1) acc += __shfl_down(acc, off, 64);
  __shared__ float part[4];
  if (lane == 0) part[group] = acc;
  __syncthreads();
  if (threadIdx.x == 0) {
    atomicAdd(out, part[0] + part[1] + part[2] + part[3]);
    if (blockIdx.x == 0) atomicAdd(out, bout[0]);
  }
}

extern "C" void kernel_launch(void* const* d_in, const int* in_sizes, int n_in,
                              void* d_out, int out_size, void* d_ws, size_t ws_size,
                              hipStream_t stream) {
  const float* emb  = (const float*)d_in[0];
  const float* deg  = (const float*)d_in[1];
  const float* seed = (const float*)d_in[2];
  const int*   row  = (const int*)d_in[3];
  const int*   col  = (const int*)d_in[4];
  const float* vals = (const float*)d_in[5];
  const float* W1   = (const float*)d_in[6];
  const float* b1   = (const float*)d_in[7];
  const float* W2   = (const float*)d_in[8];
  const float* b2   = (const float*)d_in[9];
  const float* Wout = (const float*)d_in[10];
  const float* bout = (const float*)d_in[11];
  float* out = (float*)d_out;

  const int n  = in_sizes[0] / IN_EMB;   // 100000
  const int nE = in_sizes[3];            // 3200000

  // ---- workspace layout (byte offsets, 16B-aligned chunks) ----
  char* ws = (char*)d_ws;
  const size_t buf_bytes = (size_t)n * HID * sizeof(float);          // 25.6 MB
  float* xa      = (float*)ws;                 ws += buf_bytes;
  float* yb      = (float*)ws;                 ws += buf_bytes;
  int2*  ce      = (int2*)ws;                  ws += (size_t)nE * sizeof(int2);  // 25.6 MB
  int*   row_ptr = (int*)ws;                   ws += ((size_t)(n + 1) * 4 + 15) & ~15ULL;
  int*   pos     = (int*)ws;                   ws += ((size_t)n * 4 + 15) & ~15ULL;
  int*   cnt     = (int*)ws;

  const int node_blocks = (n + 31) / 32;
  const int row_blocks  = (n + 3) / 4;
  const int edge_blocks = (nE + 255) / 256;

  // ---- CSR build (amortized over both SpMMs) ----
  hipMemsetAsync(cnt, 0, (size_t)n * sizeof(int), stream);
  hist_kernel<<<edge_blocks, 256, 0, stream>>>(row, cnt, nE);
  scan_kernel<<<1, 1024, 0, stream>>>(cnt, row_ptr, pos, n);
  scatter_kernel<<<edge_blocks, 256, 0, stream>>>(row, col, vals, pos, ce, nE);

  // ---- network ----
  lin1_kernel<<<node_blocks, 256, 0, stream>>>(emb, deg, seed, W1, b1, xa, n);
  spmm_csr_kernel<<<row_blocks, 256, 0, stream>>>(row_ptr, ce, xa, yb, n);   // relu fused
  lin2_kernel<<<node_blocks, 256, 0, stream>>>(yb, W2, b2, xa, n);
  spmm_csr_kernel<<<row_blocks, 256, 0, stream>>>(row_ptr, ce, xa, yb, n);   // relu fused
  hipMemsetAsync(out, 0, sizeof(float), stream);
  final_kernel<<<1024, 256, 0, stream>>>(yb, Wout, bout, out, n);
}